// Round 7
// baseline (472.398 us; speedup 1.0000x reference)
//
#include <hip/hip_runtime.h>

#define NNODES 50000
#define EEDGES 800000
#define FIN 128
#define FH 128
#define FOUT 16
#define BN_EPS 1e-5f
#define NB 196        // ceil(50000/256) node-scan blocks
#define NBIN 391      // ceil(50000/128) bins of 128 dst nodes
#define PCH 2048      // edges per partition block
#define NPB 391       // ceil(800000/2048)
#define NTILES 1563   // ceil(50000/32) lin1 row tiles

typedef short bf16x8 __attribute__((ext_vector_type(8)));
typedef float f32x4 __attribute__((ext_vector_type(4)));

__device__ inline unsigned short tobf16(float f) {
    unsigned int u = __float_as_uint(f);
    u += 0x7fffu + ((u >> 16) & 1u);   // RNE
    return (unsigned short)(u >> 16);
}
__device__ inline float frombf16(unsigned short h) {
    return __uint_as_float(((unsigned int)h) << 16);
}
__device__ inline unsigned packbf(float f0, float f1) {
    return (unsigned)tobf16(f0) | ((unsigned)tobf16(f1) << 16);
}
__device__ inline float lo16(unsigned u) { return __uint_as_float(u << 16); }
__device__ inline float hi16(unsigned u) { return __uint_as_float(u & 0xffff0000u); }

// ---------------- K1: pack x->bf16, W->bf16; deg + bin histograms ----------------
__global__ void pack_deg_kernel(const float* __restrict__ x,
                                const float* __restrict__ Wl1, const float* __restrict__ Wr1,
                                const float* __restrict__ Wl2, const float* __restrict__ Wr2,
                                const int* __restrict__ dst,
                                unsigned short* __restrict__ xb, unsigned short* __restrict__ wb,
                                int* __restrict__ deg, int* __restrict__ binCnt) {
    int idx = blockIdx.x * 256 + threadIdx.x;
    if (idx < NNODES * FIN) {
        xb[idx] = tobf16(x[idx]);
    } else if (idx < NNODES * FIN + 36864) {
        int w = idx - NNODES * FIN;
        float v;
        if (w < 16384) v = Wl1[w];
        else if (w < 32768) v = Wr1[w - 16384];
        else if (w < 34816) v = Wl2[w - 32768];
        else v = Wr2[w - 34816];
        wb[w] = tobf16(v);
    }
    if (idx < EEDGES) {
        int d = dst[idx];
        atomicAdd(&deg[d], 1);
        atomicAdd(&binCnt[d >> 7], 1);
    }
}

// ---------------- node-degree scan (3-phase) -> rowstart ----------------
__global__ void blocksum_kernel(const int* __restrict__ deg, int* __restrict__ blockSums) {
    int idx = blockIdx.x * 256 + threadIdx.x;
    int v = (idx < NNODES) ? deg[idx] : 0;
    for (int off = 32; off; off >>= 1) v += __shfl_down(v, off, 64);
    __shared__ int sh[4];
    if ((threadIdx.x & 63) == 0) sh[threadIdx.x >> 6] = v;
    __syncthreads();
    if (threadIdx.x == 0) blockSums[blockIdx.x] = sh[0] + sh[1] + sh[2] + sh[3];
}

__global__ void scanblocks_kernel(const int* __restrict__ blockSums, int* __restrict__ blockOff) {
    __shared__ int sh[256];
    int tid = threadIdx.x;
    int v = (tid < NB) ? blockSums[tid] : 0;
    sh[tid] = v;
    __syncthreads();
    for (int off = 1; off < 256; off <<= 1) {
        int t = (tid >= off) ? sh[tid - off] : 0;
        __syncthreads();
        sh[tid] += t;
        __syncthreads();
    }
    if (tid < NB) blockOff[tid] = sh[tid] - v;
}

__global__ void blockscan_kernel(const int* __restrict__ deg, const int* __restrict__ blockOff,
                                 int* __restrict__ rowstart) {
    __shared__ int sh[256];
    int tid = threadIdx.x;
    int idx = blockIdx.x * 256 + tid;
    int v = (idx < NNODES) ? deg[idx] : 0;
    sh[tid] = v;
    __syncthreads();
    for (int off = 1; off < 256; off <<= 1) {
        int t = (tid >= off) ? sh[tid - off] : 0;
        __syncthreads();
        sh[tid] += t;
        __syncthreads();
    }
    int r = blockOff[blockIdx.x] + sh[tid] - v;
    if (idx < NNODES) rowstart[idx] = r;
    if (idx == 0) rowstart[NNODES] = EEDGES;
}

// ---------------- bin scan ----------------
__global__ void scanbins_kernel(const int* __restrict__ binCnt,
                                int* __restrict__ binStart, int* __restrict__ binFill) {
    __shared__ int sh[512];
    int t = threadIdx.x;
    int v = (t < NBIN) ? binCnt[t] : 0;
    sh[t] = v;
    __syncthreads();
    for (int off = 1; off < 512; off <<= 1) {
        int u = (t >= off) ? sh[t - off] : 0;
        __syncthreads();
        sh[t] += u;
        __syncthreads();
    }
    if (t < NBIN) { binStart[t] = sh[t] - v; binFill[t] = sh[t] - v; }
}

// ---------------- partition edges into bins (run-reserved, write-local) ----------------
__global__ void partition_kernel(const int* __restrict__ src, const int* __restrict__ dst,
                                 int* __restrict__ binFill, unsigned int* __restrict__ edgeBin) {
    __shared__ int hist[NBIN];
    __shared__ int runBase[NBIN];
    __shared__ int runFill[NBIN];
    int t = threadIdx.x;
    for (int i = t; i < NBIN; i += 256) { hist[i] = 0; runFill[i] = 0; }
    __syncthreads();
    int e0 = blockIdx.x * PCH;
    for (int i = 0; i < PCH / 256; ++i) {
        int e = e0 + i * 256 + t;
        if (e < EEDGES) atomicAdd(&hist[dst[e] >> 7], 1);
    }
    __syncthreads();
    for (int i = t; i < NBIN; i += 256) {
        int c = hist[i];
        if (c) runBase[i] = atomicAdd(&binFill[i], c);
    }
    __syncthreads();
    for (int i = 0; i < PCH / 256; ++i) {
        int e = e0 + i * 256 + t;
        if (e < EEDGES) {
            int d = dst[e];
            int b = d >> 7;
            int off = atomicAdd(&runFill[b], 1);
            edgeBin[runBase[b] + off] = ((unsigned)(d & 127) << 17) | (unsigned)src[e];
        }
    }
}

// ---------------- local bucket: one block per bin, writes stay bin-local ----------------
__global__ void local_bucket_kernel(const unsigned int* __restrict__ edgeBin,
                                    const int* __restrict__ binStart, const int* __restrict__ binCnt,
                                    const int* __restrict__ rowstart,
                                    int* __restrict__ srcSorted) {
    __shared__ int wp[128];
    int b = blockIdx.x;
    int t = threadIdx.x;
    if (t < 128) {
        int node = b * 128 + t;
        wp[t] = (node < NNODES) ? rowstart[node] : 0;
    }
    __syncthreads();
    int bs = binStart[b], cnt = binCnt[b];
    for (int k = t; k < cnt; k += 256) {
        unsigned c = edgeBin[bs + k];
        int p = atomicAdd(&wp[c >> 17], 1);
        srcSorted[p] = (int)(c & 0x1FFFF);
    }
}

// ---------------- gather 128 features (per-node, register accum) ----------------
__global__ void gather_bf16(const unsigned short* __restrict__ feat,
                            const int* __restrict__ rowstart,
                            const int* __restrict__ srcSorted,
                            unsigned short* __restrict__ aggout) {
    int tid = threadIdx.x;
    int i = blockIdx.x * 4 + (tid >> 6);
    int j = tid & 63;
    const unsigned int* fp = (const unsigned int*)feat;
    int k0 = rowstart[i], k1 = rowstart[i + 1];
    float a0 = 0.0f, a1 = 0.0f;
    int k = k0;
    for (; k + 4 <= k1; k += 4) {
        int s0 = srcSorted[k], s1 = srcSorted[k + 1], s2 = srcSorted[k + 2], s3 = srcSorted[k + 3];
        unsigned int u0 = fp[(size_t)s0 * 64 + j];
        unsigned int u1 = fp[(size_t)s1 * 64 + j];
        unsigned int u2 = fp[(size_t)s2 * 64 + j];
        unsigned int u3 = fp[(size_t)s3 * 64 + j];
        a0 += lo16(u0) + lo16(u1) + lo16(u2) + lo16(u3);
        a1 += hi16(u0) + hi16(u1) + hi16(u2) + hi16(u3);
    }
    for (; k < k1; ++k) {
        unsigned int u = fp[(size_t)srcSorted[k] * 64 + j];
        a0 += lo16(u);
        a1 += hi16(u);
    }
    float inv = 1.0f / (float)max(k1 - k0, 1);
    ((unsigned int*)aggout)[(size_t)i * 64 + j] = packbf(a0 * inv, a1 * inv);
}

// ---------------- lin1: persistent-weight MFMA + fused BN partials ----------------
// 512 blocks x 4 waves, grid-stride over 32-row tiles. Each wave holds a 64-col
// half of BOTH Wl and Wr in registers (32 bf16x8 frags = 128 VGPR) for the whole
// kernel; per tile only 8 A-loads + 32 MFMA.
__global__ void __launch_bounds__(256, 2)
lin1_persist(const unsigned short* __restrict__ aggb,
             const unsigned short* __restrict__ xb,
             const unsigned short* __restrict__ wl,
             const unsigned short* __restrict__ wr,
             const float* __restrict__ bias,
             unsigned short* __restrict__ hb,
             float* __restrict__ bnsum, float* __restrict__ bnsq) {
    __shared__ float bps[128];
    __shared__ float bpq[128];
    int tid = threadIdx.x;
    if (tid < 128) { bps[tid] = 0.0f; bpq[tid] = 0.0f; }
    __syncthreads();
    int wave = tid >> 6;
    int lane = tid & 63;
    int c = wave & 1;        // column half: cols c*64 .. c*64+63
    int rsub = wave >> 1;    // row half within 32-row tile
    int lrow = lane & 15;
    int kg = lane >> 4;

    // persistent weight fragments
    bf16x8 wlF[4][4], wrF[4][4];
    #pragma unroll
    for (int nf = 0; nf < 4; ++nf) {
        #pragma unroll
        for (int ks = 0; ks < 4; ++ks) {
            wlF[nf][ks] = *(const bf16x8*)(wl + (size_t)(c * 64 + nf * 16 + lrow) * 128 + ks * 32 + kg * 8);
            wrF[nf][ks] = *(const bf16x8*)(wr + (size_t)(c * 64 + nf * 16 + lrow) * 128 + ks * 32 + kg * 8);
        }
    }
    float bias_v[4];
    #pragma unroll
    for (int nf = 0; nf < 4; ++nf) bias_v[nf] = bias[c * 64 + nf * 16 + lrow];

    for (int tIt = blockIdx.x; tIt < NTILES; tIt += gridDim.x) {
        int rowA = tIt * 32 + rsub * 16 + lrow;
        int arow = min(rowA, NNODES - 1);
        bf16x8 aA[4], aX[4];
        #pragma unroll
        for (int ks = 0; ks < 4; ++ks) {
            aA[ks] = *(const bf16x8*)(aggb + (size_t)arow * 128 + ks * 32 + kg * 8);
            aX[ks] = *(const bf16x8*)(xb + (size_t)arow * 128 + ks * 32 + kg * 8);
        }
        f32x4 acc[4] = {};
        #pragma unroll
        for (int ks = 0; ks < 4; ++ks) {
            #pragma unroll
            for (int nf = 0; nf < 4; ++nf) {
                acc[nf] = __builtin_amdgcn_mfma_f32_16x16x32_bf16(aA[ks], wlF[nf][ks], acc[nf], 0, 0, 0);
                acc[nf] = __builtin_amdgcn_mfma_f32_16x16x32_bf16(aX[ks], wrF[nf][ks], acc[nf], 0, 0, 0);
            }
        }
        #pragma unroll
        for (int nf = 0; nf < 4; ++nf) {
            float s = 0.0f, q = 0.0f;
            #pragma unroll
            for (int rr = 0; rr < 4; ++rr) {
                int row = tIt * 32 + rsub * 16 + kg * 4 + rr;
                if (row < NNODES) {
                    unsigned short hv = tobf16(acc[nf][rr] + bias_v[nf]);
                    float vr = frombf16(hv);
                    hb[(size_t)row * 128 + c * 64 + nf * 16 + lrow] = hv;
                    s += vr; q += vr * vr;
                }
            }
            s += __shfl_xor(s, 16); s += __shfl_xor(s, 32);
            q += __shfl_xor(q, 16); q += __shfl_xor(q, 32);
            if (lane < 16) {
                atomicAdd(&bps[c * 64 + nf * 16 + lane], s);
                atomicAdd(&bpq[c * 64 + nf * 16 + lane], q);
            }
        }
    }
    __syncthreads();
    if (tid < 128) {
        atomicAdd(&bnsum[tid], bps[tid]);
        atomicAdd(&bnsq[tid], bpq[tid]);
    }
}

// ---------------- BN apply + PReLU + residual (bf16 x), in place on hb ----------------
__global__ void bn_apply_kernel(unsigned short* __restrict__ hb,
                                const unsigned short* __restrict__ xb,
                                const float* __restrict__ gamma, const float* __restrict__ beta,
                                const float* __restrict__ aptr,
                                const float* __restrict__ bnsum, const float* __restrict__ bnsq) {
    int idx = blockIdx.x * 256 + threadIdx.x;
    if (idx >= NNODES * FH) return;
    int j = idx & 127;
    const float invN = 1.0f / (float)NNODES;
    float mean = bnsum[j] * invN;
    float var = bnsq[j] * invN - mean * mean;
    float istd = rsqrtf(var + BN_EPS);
    float v = frombf16(hb[idx]);
    v = gamma[j] * (v - mean) * istd + beta[j];
    float a = aptr[0];
    v = (v >= 0.0f) ? v : a * v;
    hb[idx] = tobf16(v + frombf16(xb[idx]));
}

// ---------------- y2 = hb @ Wl2^T (bf16 out, [N,16]) ----------------
__global__ void lin2a_kernel(const unsigned short* __restrict__ hb,
                             const unsigned short* __restrict__ wl,
                             unsigned short* __restrict__ y2) {
    int wave = threadIdx.x >> 6;
    int lane = threadIdx.x & 63;
    int row0 = blockIdx.x * 64 + wave * 16;
    int lrow = lane & 15;
    int kg = lane >> 4;
    int arow = min(row0 + lrow, NNODES - 1);
    f32x4 acc = {};
    #pragma unroll
    for (int ks = 0; ks < 4; ++ks) {
        bf16x8 a = *(const bf16x8*)(hb + (size_t)arow * 128 + ks * 32 + kg * 8);
        bf16x8 b = *(const bf16x8*)(wl + (size_t)lrow * 128 + ks * 32 + kg * 8);
        acc = __builtin_amdgcn_mfma_f32_16x16x32_bf16(a, b, acc, 0, 0, 0);
    }
    #pragma unroll
    for (int r = 0; r < 4; ++r) {
        int row = row0 + kg * 4 + r;
        if (row < NNODES)
            y2[(size_t)row * 16 + lrow] = tobf16(acc[r]);
    }
}

// ---------------- gather 16 features (8 lanes/edge, 8 edges in flight) ----------------
__global__ void gather16_kernel(const unsigned short* __restrict__ y2,
                                const int* __restrict__ rowstart,
                                const int* __restrict__ srcSorted,
                                unsigned short* __restrict__ agg2) {
    int tid = threadIdx.x;
    int i = blockIdx.x * 4 + (tid >> 6);
    int lane = tid & 63;
    int e = lane >> 3;
    int j = lane & 7;
    const unsigned int* yp = (const unsigned int*)y2;
    int k0 = rowstart[i], k1 = rowstart[i + 1];
    float a0 = 0.0f, a1 = 0.0f;
    for (int k = k0; k < k1; k += 8) {
        int kk = k + e;
        if (kk < k1) {
            unsigned u = yp[(size_t)srcSorted[kk] * 8 + j];
            a0 += lo16(u);
            a1 += hi16(u);
        }
    }
    a0 += __shfl_xor(a0, 8);  a1 += __shfl_xor(a1, 8);
    a0 += __shfl_xor(a0, 16); a1 += __shfl_xor(a1, 16);
    a0 += __shfl_xor(a0, 32); a1 += __shfl_xor(a1, 32);
    if (e == 0) {
        float inv = 1.0f / (float)max(k1 - k0, 1);
        ((unsigned int*)agg2)[(size_t)i * 8 + j] = packbf(a0 * inv, a1 * inv);
    }
}

// ---------------- out = agg2 + hb@Wr2^T + bl2 -> log_softmax ----------------
__global__ void lin2b_kernel(const unsigned short* __restrict__ agg2,
                             const unsigned short* __restrict__ hb,
                             const unsigned short* __restrict__ wr,
                             const float* __restrict__ bias,
                             float* __restrict__ out) {
    int wave = threadIdx.x >> 6;
    int lane = threadIdx.x & 63;
    int row0 = blockIdx.x * 64 + wave * 16;
    int lrow = lane & 15;
    int kg = lane >> 4;
    int arow = min(row0 + lrow, NNODES - 1);
    f32x4 acc = {};
    #pragma unroll
    for (int ks = 0; ks < 4; ++ks) {
        bf16x8 a = *(const bf16x8*)(hb + (size_t)arow * 128 + ks * 32 + kg * 8);
        bf16x8 b = *(const bf16x8*)(wr + (size_t)lrow * 128 + ks * 32 + kg * 8);
        acc = __builtin_amdgcn_mfma_f32_16x16x32_bf16(a, b, acc, 0, 0, 0);
    }
    float bl = bias[lrow];
    #pragma unroll
    for (int r = 0; r < 4; ++r) {
        int row = row0 + kg * 4 + r;
        int rowc = min(row, NNODES - 1);
        float v = acc[r] + bl + frombf16(agg2[(size_t)rowc * 16 + lrow]);
        float m = v;
        for (int s = 1; s < 16; s <<= 1) m = fmaxf(m, __shfl_xor(m, s, 16));
        float ex = expf(v - m);
        float se = ex;
        for (int s = 1; s < 16; s <<= 1) se += __shfl_xor(se, s, 16);
        if (row < NNODES)
            out[(size_t)row * FOUT + lrow] = v - m - logf(se);
    }
}

extern "C" void kernel_launch(void* const* d_in, const int* in_sizes, int n_in,
                              void* d_out, int out_size, void* d_ws, size_t ws_size,
                              hipStream_t stream) {
    const float* x    = (const float*)d_in[0];
    const int*   ei   = (const int*)d_in[1];
    const int*   src  = ei;
    const int*   dst  = ei + EEDGES;
    const float* Wl1  = (const float*)d_in[2];
    const float* bl1  = (const float*)d_in[3];
    const float* Wr1  = (const float*)d_in[4];
    const float* Wl2  = (const float*)d_in[5];
    const float* bl2  = (const float*)d_in[6];
    const float* Wr2  = (const float*)d_in[7];
    const float* gamma= (const float*)d_in[8];
    const float* beta = (const float*)d_in[9];
    const float* a    = (const float*)d_in[10];
    float* out = (float*)d_out;

    char* W = (char*)d_ws;
    unsigned short* xb    = (unsigned short*)(W + 0);           // 12,800,000 B
    unsigned short* hb    = (unsigned short*)(W + 12800000);    // 12,800,000 B
    unsigned int*  edgeBin= (unsigned int*)(W + 25600000);      // 3,200,000 B (dead after local_bucket)
    unsigned short* aggb  = (unsigned short*)(W + 25600000);    // 12,800,000 B (overlays edgeBin, layer1)
    unsigned short* y2b   = (unsigned short*)(W + 25600000);    // 1,600,000 B (overlays aggb)
    unsigned short* agg2b = (unsigned short*)(W + 27200000);    // 1,600,000 B
    unsigned short* wb    = (unsigned short*)(W + 38400000);    // 73,728 B
    int* deg      = (int*)(W + 38473728);                       // 200,000 B
    int* binCnt   = (int*)(W + 38673728);                       // 1,564 B
    float* bnsum  = (float*)(W + 38675292);                     // 512 B
    float* bnsq   = (float*)(W + 38675804);                     // 512 B
    int* binStart = (int*)(W + 38676316);                       // 1,564 B
    int* binFill  = (int*)(W + 38677880);                       // 1,564 B
    int* rowstart = (int*)(W + 38679444);                       // 200,004 B
    int* blockSums= (int*)(W + 38879448);                       // 784 B
    int* blockOff = (int*)(W + 38880232);                       // 784 B
    int* srcSorted= (int*)(W + 38881016);                       // 3,200,000 B -> end 42,081,016

    unsigned short* wl1b = wb;
    unsigned short* wr1b = wb + 16384;
    unsigned short* wl2b = wb + 32768;
    unsigned short* wr2b = wb + 34816;

    // zero deg + binCnt + bnsum + bnsq (contiguous: 202,588 B)
    hipMemsetAsync(deg, 0, (size_t)202588, stream);

    pack_deg_kernel<<<25145, 256, 0, stream>>>(x, Wl1, Wr1, Wl2, Wr2, dst, xb, wb, deg, binCnt);

    blocksum_kernel<<<NB, 256, 0, stream>>>(deg, blockSums);
    scanblocks_kernel<<<1, 256, 0, stream>>>(blockSums, blockOff);
    blockscan_kernel<<<NB, 256, 0, stream>>>(deg, blockOff, rowstart);
    scanbins_kernel<<<1, 512, 0, stream>>>(binCnt, binStart, binFill);
    partition_kernel<<<NPB, 256, 0, stream>>>(src, dst, binFill, edgeBin);
    local_bucket_kernel<<<NBIN, 256, 0, stream>>>(edgeBin, binStart, binCnt, rowstart, srcSorted);

    // layer 1
    gather_bf16<<<NNODES / 4, 256, 0, stream>>>(xb, rowstart, srcSorted, aggb);
    lin1_persist<<<512, 256, 0, stream>>>(aggb, xb, wl1b, wr1b, bl1, hb, bnsum, bnsq);
    bn_apply_kernel<<<25000, 256, 0, stream>>>(hb, xb, gamma, beta, a, bnsum, bnsq);

    // layer 2 (transform-then-aggregate)
    lin2a_kernel<<<782, 256, 0, stream>>>(hb, wl2b, y2b);
    gather16_kernel<<<NNODES / 4, 256, 0, stream>>>(y2b, rowstart, srcSorted, agg2b);
    lin2b_kernel<<<782, 256, 0, stream>>>(agg2b, hb, wr2b, bl2, out);
}

// Round 8
// 204.043 us; speedup vs baseline: 2.3152x; 2.3152x over previous
//
#include <hip/hip_runtime.h>

#define NNODES 50000
#define EEDGES 800000
#define FIN 128
#define FH 128
#define FOUT 16
#define BN_EPS 1e-5f
#define NB 196        // ceil(50000/256) node-scan blocks
#define NBIN 391      // ceil(50000/128) bins of 128 dst nodes
#define PCH 2048      // edges per partition block
#define NPB 391       // ceil(800000/2048)
#define NTILES 1563   // ceil(50000/32) lin1 row tiles

typedef short bf16x8 __attribute__((ext_vector_type(8)));
typedef float f32x4 __attribute__((ext_vector_type(4)));

__device__ inline unsigned short tobf16(float f) {
    unsigned int u = __float_as_uint(f);
    u += 0x7fffu + ((u >> 16) & 1u);   // RNE
    return (unsigned short)(u >> 16);
}
__device__ inline float frombf16(unsigned short h) {
    return __uint_as_float(((unsigned int)h) << 16);
}
__device__ inline unsigned packbf(float f0, float f1) {
    return (unsigned)tobf16(f0) | ((unsigned)tobf16(f1) << 16);
}
__device__ inline float lo16(unsigned u) { return __uint_as_float(u << 16); }
__device__ inline float hi16(unsigned u) { return __uint_as_float(u & 0xffff0000u); }

// ---------------- K1: pack x->bf16, W->bf16; deg histogram (50K-way, cheap) ----------------
__global__ void pack_deg_kernel(const float* __restrict__ x,
                                const float* __restrict__ Wl1, const float* __restrict__ Wr1,
                                const float* __restrict__ Wl2, const float* __restrict__ Wr2,
                                const int* __restrict__ dst,
                                unsigned short* __restrict__ xb, unsigned short* __restrict__ wb,
                                int* __restrict__ deg) {
    int idx = blockIdx.x * 256 + threadIdx.x;
    if (idx < NNODES * FIN) {
        xb[idx] = tobf16(x[idx]);
    } else if (idx < NNODES * FIN + 36864) {
        int w = idx - NNODES * FIN;
        float v;
        if (w < 16384) v = Wl1[w];
        else if (w < 32768) v = Wr1[w - 16384];
        else if (w < 34816) v = Wl2[w - 32768];
        else v = Wr2[w - 34816];
        wb[w] = tobf16(v);
    }
    if (idx < EEDGES) atomicAdd(&deg[dst[idx]], 1);
}

// ---------------- node-degree scan (3-phase) -> rowstart ----------------
__global__ void blocksum_kernel(const int* __restrict__ deg, int* __restrict__ blockSums) {
    int idx = blockIdx.x * 256 + threadIdx.x;
    int v = (idx < NNODES) ? deg[idx] : 0;
    for (int off = 32; off; off >>= 1) v += __shfl_down(v, off, 64);
    __shared__ int sh[4];
    if ((threadIdx.x & 63) == 0) sh[threadIdx.x >> 6] = v;
    __syncthreads();
    if (threadIdx.x == 0) blockSums[blockIdx.x] = sh[0] + sh[1] + sh[2] + sh[3];
}

__global__ void scanblocks_kernel(const int* __restrict__ blockSums, int* __restrict__ blockOff) {
    __shared__ int sh[256];
    int tid = threadIdx.x;
    int v = (tid < NB) ? blockSums[tid] : 0;
    sh[tid] = v;
    __syncthreads();
    for (int off = 1; off < 256; off <<= 1) {
        int t = (tid >= off) ? sh[tid - off] : 0;
        __syncthreads();
        sh[tid] += t;
        __syncthreads();
    }
    if (tid < NB) blockOff[tid] = sh[tid] - v;
}

__global__ void blockscan_kernel(const int* __restrict__ deg, const int* __restrict__ blockOff,
                                 int* __restrict__ rowstart) {
    __shared__ int sh[256];
    int tid = threadIdx.x;
    int idx = blockIdx.x * 256 + tid;
    int v = (idx < NNODES) ? deg[idx] : 0;
    sh[tid] = v;
    __syncthreads();
    for (int off = 1; off < 256; off <<= 1) {
        int t = (tid >= off) ? sh[tid - off] : 0;
        __syncthreads();
        sh[tid] += t;
        __syncthreads();
    }
    int r = blockOff[blockIdx.x] + sh[tid] - v;
    if (idx < NNODES) rowstart[idx] = r;
    if (idx == 0) rowstart[NNODES] = EEDGES;
}

// ---------------- bins derived from rowstart (no atomics) ----------------
__global__ void binsetup_kernel(const int* __restrict__ rowstart,
                                int* __restrict__ binStart, int* __restrict__ binFill,
                                int* __restrict__ binCnt) {
    int b = threadIdx.x;
    if (b < NBIN) {
        int s = rowstart[b * 128];
        int e = rowstart[min((b + 1) * 128, NNODES)];
        binStart[b] = s;
        binFill[b] = s;
        binCnt[b] = e - s;
    }
}

// ---------------- partition edges into bins (run-reserved, write-local) ----------------
__global__ void partition_kernel(const int* __restrict__ src, const int* __restrict__ dst,
                                 int* __restrict__ binFill, unsigned int* __restrict__ edgeBin) {
    __shared__ int hist[NBIN];
    __shared__ int runBase[NBIN];
    __shared__ int runFill[NBIN];
    int t = threadIdx.x;
    for (int i = t; i < NBIN; i += 256) { hist[i] = 0; runFill[i] = 0; }
    __syncthreads();
    int e0 = blockIdx.x * PCH;
    for (int i = 0; i < PCH / 256; ++i) {
        int e = e0 + i * 256 + t;
        if (e < EEDGES) atomicAdd(&hist[dst[e] >> 7], 1);
    }
    __syncthreads();
    for (int i = t; i < NBIN; i += 256) {
        int c = hist[i];
        if (c) runBase[i] = atomicAdd(&binFill[i], c);
    }
    __syncthreads();
    for (int i = 0; i < PCH / 256; ++i) {
        int e = e0 + i * 256 + t;
        if (e < EEDGES) {
            int d = dst[e];
            int b = d >> 7;
            int off = atomicAdd(&runFill[b], 1);
            edgeBin[runBase[b] + off] = ((unsigned)(d & 127) << 17) | (unsigned)src[e];
        }
    }
}

// ---------------- local bucket: one block per bin, writes stay bin-local ----------------
__global__ void local_bucket_kernel(const unsigned int* __restrict__ edgeBin,
                                    const int* __restrict__ binStart, const int* __restrict__ binCnt,
                                    const int* __restrict__ rowstart,
                                    int* __restrict__ srcSorted) {
    __shared__ int wp[128];
    int b = blockIdx.x;
    int t = threadIdx.x;
    if (t < 128) {
        int node = b * 128 + t;
        wp[t] = (node < NNODES) ? rowstart[node] : 0;
    }
    __syncthreads();
    int bs = binStart[b], cnt = binCnt[b];
    for (int k = t; k < cnt; k += 256) {
        unsigned c = edgeBin[bs + k];
        int p = atomicAdd(&wp[c >> 17], 1);
        srcSorted[p] = (int)(c & 0x1FFFF);
    }
}

// ---------------- gather 128 features (per-node, register accum) ----------------
__global__ void gather_bf16(const unsigned short* __restrict__ feat,
                            const int* __restrict__ rowstart,
                            const int* __restrict__ srcSorted,
                            unsigned short* __restrict__ aggout) {
    int tid = threadIdx.x;
    int i = blockIdx.x * 4 + (tid >> 6);
    int j = tid & 63;
    const unsigned int* fp = (const unsigned int*)feat;
    int k0 = rowstart[i], k1 = rowstart[i + 1];
    float a0 = 0.0f, a1 = 0.0f;
    int k = k0;
    for (; k + 4 <= k1; k += 4) {
        int s0 = srcSorted[k], s1 = srcSorted[k + 1], s2 = srcSorted[k + 2], s3 = srcSorted[k + 3];
        unsigned int u0 = fp[(size_t)s0 * 64 + j];
        unsigned int u1 = fp[(size_t)s1 * 64 + j];
        unsigned int u2 = fp[(size_t)s2 * 64 + j];
        unsigned int u3 = fp[(size_t)s3 * 64 + j];
        a0 += lo16(u0) + lo16(u1) + lo16(u2) + lo16(u3);
        a1 += hi16(u0) + hi16(u1) + hi16(u2) + hi16(u3);
    }
    for (; k < k1; ++k) {
        unsigned int u = fp[(size_t)srcSorted[k] * 64 + j];
        a0 += lo16(u);
        a1 += hi16(u);
    }
    float inv = 1.0f / (float)max(k1 - k0, 1);
    ((unsigned int*)aggout)[(size_t)i * 64 + j] = packbf(a0 * inv, a1 * inv);
}

// ---------------- lin1: persistent-weight MFMA + fused BN partials ----------------
__global__ void __launch_bounds__(256, 2)
lin1_persist(const unsigned short* __restrict__ aggb,
             const unsigned short* __restrict__ xb,
             const unsigned short* __restrict__ wl,
             const unsigned short* __restrict__ wr,
             const float* __restrict__ bias,
             unsigned short* __restrict__ hb,
             float* __restrict__ bnsum, float* __restrict__ bnsq) {
    __shared__ float bps[128];
    __shared__ float bpq[128];
    int tid = threadIdx.x;
    if (tid < 128) { bps[tid] = 0.0f; bpq[tid] = 0.0f; }
    __syncthreads();
    int wave = tid >> 6;
    int lane = tid & 63;
    int c = wave & 1;        // column half
    int rsub = wave >> 1;    // row half within 32-row tile
    int lrow = lane & 15;
    int kg = lane >> 4;

    bf16x8 wlF[4][4], wrF[4][4];
    #pragma unroll
    for (int nf = 0; nf < 4; ++nf) {
        #pragma unroll
        for (int ks = 0; ks < 4; ++ks) {
            wlF[nf][ks] = *(const bf16x8*)(wl + (size_t)(c * 64 + nf * 16 + lrow) * 128 + ks * 32 + kg * 8);
            wrF[nf][ks] = *(const bf16x8*)(wr + (size_t)(c * 64 + nf * 16 + lrow) * 128 + ks * 32 + kg * 8);
        }
    }
    float bias_v[4];
    #pragma unroll
    for (int nf = 0; nf < 4; ++nf) bias_v[nf] = bias[c * 64 + nf * 16 + lrow];

    for (int tIt = blockIdx.x; tIt < NTILES; tIt += gridDim.x) {
        int rowA = tIt * 32 + rsub * 16 + lrow;
        int arow = min(rowA, NNODES - 1);
        bf16x8 aA[4], aX[4];
        #pragma unroll
        for (int ks = 0; ks < 4; ++ks) {
            aA[ks] = *(const bf16x8*)(aggb + (size_t)arow * 128 + ks * 32 + kg * 8);
            aX[ks] = *(const bf16x8*)(xb + (size_t)arow * 128 + ks * 32 + kg * 8);
        }
        f32x4 acc[4] = {};
        #pragma unroll
        for (int ks = 0; ks < 4; ++ks) {
            #pragma unroll
            for (int nf = 0; nf < 4; ++nf) {
                acc[nf] = __builtin_amdgcn_mfma_f32_16x16x32_bf16(aA[ks], wlF[nf][ks], acc[nf], 0, 0, 0);
                acc[nf] = __builtin_amdgcn_mfma_f32_16x16x32_bf16(aX[ks], wrF[nf][ks], acc[nf], 0, 0, 0);
            }
        }
        #pragma unroll
        for (int nf = 0; nf < 4; ++nf) {
            float s = 0.0f, q = 0.0f;
            #pragma unroll
            for (int rr = 0; rr < 4; ++rr) {
                int row = tIt * 32 + rsub * 16 + kg * 4 + rr;
                if (row < NNODES) {
                    unsigned short hv = tobf16(acc[nf][rr] + bias_v[nf]);
                    float vr = frombf16(hv);
                    hb[(size_t)row * 128 + c * 64 + nf * 16 + lrow] = hv;
                    s += vr; q += vr * vr;
                }
            }
            s += __shfl_xor(s, 16); s += __shfl_xor(s, 32);
            q += __shfl_xor(q, 16); q += __shfl_xor(q, 32);
            if (lane < 16) {
                atomicAdd(&bps[c * 64 + nf * 16 + lane], s);
                atomicAdd(&bpq[c * 64 + nf * 16 + lane], q);
            }
        }
    }
    __syncthreads();
    if (tid < 128) {
        atomicAdd(&bnsum[tid], bps[tid]);
        atomicAdd(&bnsq[tid], bpq[tid]);
    }
}

// ---------------- BN apply + PReLU + residual (bf16 x), in place on hb ----------------
__global__ void bn_apply_kernel(unsigned short* __restrict__ hb,
                                const unsigned short* __restrict__ xb,
                                const float* __restrict__ gamma, const float* __restrict__ beta,
                                const float* __restrict__ aptr,
                                const float* __restrict__ bnsum, const float* __restrict__ bnsq) {
    int idx = blockIdx.x * 256 + threadIdx.x;
    if (idx >= NNODES * FH) return;
    int j = idx & 127;
    const float invN = 1.0f / (float)NNODES;
    float mean = bnsum[j] * invN;
    float var = bnsq[j] * invN - mean * mean;
    float istd = rsqrtf(var + BN_EPS);
    float v = frombf16(hb[idx]);
    v = gamma[j] * (v - mean) * istd + beta[j];
    float a = aptr[0];
    v = (v >= 0.0f) ? v : a * v;
    hb[idx] = tobf16(v + frombf16(xb[idx]));
}

// ---------------- y2 = hb @ Wl2^T (bf16 out, [N,16]) ----------------
__global__ void lin2a_kernel(const unsigned short* __restrict__ hb,
                             const unsigned short* __restrict__ wl,
                             unsigned short* __restrict__ y2) {
    int wave = threadIdx.x >> 6;
    int lane = threadIdx.x & 63;
    int row0 = blockIdx.x * 64 + wave * 16;
    int lrow = lane & 15;
    int kg = lane >> 4;
    int arow = min(row0 + lrow, NNODES - 1);
    f32x4 acc = {};
    #pragma unroll
    for (int ks = 0; ks < 4; ++ks) {
        bf16x8 a = *(const bf16x8*)(hb + (size_t)arow * 128 + ks * 32 + kg * 8);
        bf16x8 b = *(const bf16x8*)(wl + (size_t)lrow * 128 + ks * 32 + kg * 8);
        acc = __builtin_amdgcn_mfma_f32_16x16x32_bf16(a, b, acc, 0, 0, 0);
    }
    #pragma unroll
    for (int r = 0; r < 4; ++r) {
        int row = row0 + kg * 4 + r;
        if (row < NNODES)
            y2[(size_t)row * 16 + lrow] = tobf16(acc[r]);
    }
}

// ---------------- gather 16 features (8 lanes/edge, 8 edges in flight) ----------------
__global__ void gather16_kernel(const unsigned short* __restrict__ y2,
                                const int* __restrict__ rowstart,
                                const int* __restrict__ srcSorted,
                                unsigned short* __restrict__ agg2) {
    int tid = threadIdx.x;
    int i = blockIdx.x * 4 + (tid >> 6);
    int lane = tid & 63;
    int e = lane >> 3;
    int j = lane & 7;
    const unsigned int* yp = (const unsigned int*)y2;
    int k0 = rowstart[i], k1 = rowstart[i + 1];
    float a0 = 0.0f, a1 = 0.0f;
    for (int k = k0; k < k1; k += 8) {
        int kk = k + e;
        if (kk < k1) {
            unsigned u = yp[(size_t)srcSorted[kk] * 8 + j];
            a0 += lo16(u);
            a1 += hi16(u);
        }
    }
    a0 += __shfl_xor(a0, 8);  a1 += __shfl_xor(a1, 8);
    a0 += __shfl_xor(a0, 16); a1 += __shfl_xor(a1, 16);
    a0 += __shfl_xor(a0, 32); a1 += __shfl_xor(a1, 32);
    if (e == 0) {
        float inv = 1.0f / (float)max(k1 - k0, 1);
        ((unsigned int*)agg2)[(size_t)i * 8 + j] = packbf(a0 * inv, a1 * inv);
    }
}

// ---------------- out = agg2 + hb@Wr2^T + bl2 -> log_softmax ----------------
__global__ void lin2b_kernel(const unsigned short* __restrict__ agg2,
                             const unsigned short* __restrict__ hb,
                             const unsigned short* __restrict__ wr,
                             const float* __restrict__ bias,
                             float* __restrict__ out) {
    int wave = threadIdx.x >> 6;
    int lane = threadIdx.x & 63;
    int row0 = blockIdx.x * 64 + wave * 16;
    int lrow = lane & 15;
    int kg = lane >> 4;
    int arow = min(row0 + lrow, NNODES - 1);
    f32x4 acc = {};
    #pragma unroll
    for (int ks = 0; ks < 4; ++ks) {
        bf16x8 a = *(const bf16x8*)(hb + (size_t)arow * 128 + ks * 32 + kg * 8);
        bf16x8 b = *(const bf16x8*)(wr + (size_t)lrow * 128 + ks * 32 + kg * 8);
        acc = __builtin_amdgcn_mfma_f32_16x16x32_bf16(a, b, acc, 0, 0, 0);
    }
    float bl = bias[lrow];
    #pragma unroll
    for (int r = 0; r < 4; ++r) {
        int row = row0 + kg * 4 + r;
        int rowc = min(row, NNODES - 1);
        float v = acc[r] + bl + frombf16(agg2[(size_t)rowc * 16 + lrow]);
        float m = v;
        for (int s = 1; s < 16; s <<= 1) m = fmaxf(m, __shfl_xor(m, s, 16));
        float ex = expf(v - m);
        float se = ex;
        for (int s = 1; s < 16; s <<= 1) se += __shfl_xor(se, s, 16);
        if (row < NNODES)
            out[(size_t)row * FOUT + lrow] = v - m - logf(se);
    }
}

extern "C" void kernel_launch(void* const* d_in, const int* in_sizes, int n_in,
                              void* d_out, int out_size, void* d_ws, size_t ws_size,
                              hipStream_t stream) {
    const float* x    = (const float*)d_in[0];
    const int*   ei   = (const int*)d_in[1];
    const int*   src  = ei;
    const int*   dst  = ei + EEDGES;
    const float* Wl1  = (const float*)d_in[2];
    const float* bl1  = (const float*)d_in[3];
    const float* Wr1  = (const float*)d_in[4];
    const float* Wl2  = (const float*)d_in[5];
    const float* bl2  = (const float*)d_in[6];
    const float* Wr2  = (const float*)d_in[7];
    const float* gamma= (const float*)d_in[8];
    const float* beta = (const float*)d_in[9];
    const float* a    = (const float*)d_in[10];
    float* out = (float*)d_out;

    char* W = (char*)d_ws;
    unsigned short* xb    = (unsigned short*)(W + 0);           // 12,800,000 B
    unsigned short* hb    = (unsigned short*)(W + 12800000);    // 12,800,000 B
    unsigned int*  edgeBin= (unsigned int*)(W + 25600000);      // 3,200,000 B (dead after local_bucket)
    unsigned short* aggb  = (unsigned short*)(W + 25600000);    // 12,800,000 B (overlays edgeBin, layer1)
    unsigned short* y2b   = (unsigned short*)(W + 25600000);    // 1,600,000 B (overlays aggb)
    unsigned short* agg2b = (unsigned short*)(W + 27200000);    // 1,600,000 B
    unsigned short* wb    = (unsigned short*)(W + 38400000);    // 73,728 B
    int* deg      = (int*)(W + 38473728);                       // 200,000 B
    int* binCnt   = (int*)(W + 38673728);                       // 1,564 B
    float* bnsum  = (float*)(W + 38675292);                     // 512 B
    float* bnsq   = (float*)(W + 38675804);                     // 512 B
    int* binStart = (int*)(W + 38676316);                       // 1,564 B
    int* binFill  = (int*)(W + 38677880);                       // 1,564 B
    int* rowstart = (int*)(W + 38679444);                       // 200,004 B
    int* blockSums= (int*)(W + 38879448);                       // 784 B
    int* blockOff = (int*)(W + 38880232);                       // 784 B
    int* srcSorted= (int*)(W + 38881016);                       // 3,200,000 B

    unsigned short* wl1b = wb;
    unsigned short* wr1b = wb + 16384;
    unsigned short* wl2b = wb + 32768;
    unsigned short* wr2b = wb + 34816;

    // zero deg..bnsq (contiguous: 202,588 B; includes unused binCnt region, harmless)
    hipMemsetAsync(deg, 0, (size_t)202588, stream);

    pack_deg_kernel<<<25145, 256, 0, stream>>>(x, Wl1, Wr1, Wl2, Wr2, dst, xb, wb, deg);

    blocksum_kernel<<<NB, 256, 0, stream>>>(deg, blockSums);
    scanblocks_kernel<<<1, 256, 0, stream>>>(blockSums, blockOff);
    blockscan_kernel<<<NB, 256, 0, stream>>>(deg, blockOff, rowstart);
    binsetup_kernel<<<1, 512, 0, stream>>>(rowstart, binStart, binFill, binCnt);
    partition_kernel<<<NPB, 256, 0, stream>>>(src, dst, binFill, edgeBin);
    local_bucket_kernel<<<NBIN, 256, 0, stream>>>(edgeBin, binStart, binCnt, rowstart, srcSorted);

    // layer 1
    gather_bf16<<<NNODES / 4, 256, 0, stream>>>(xb, rowstart, srcSorted, aggb);
    lin1_persist<<<512, 256, 0, stream>>>(aggb, xb, wl1b, wr1b, bl1, hb, bnsum, bnsq);
    bn_apply_kernel<<<25000, 256, 0, stream>>>(hb, xb, gamma, beta, a, bnsum, bnsq);

    // layer 2 (transform-then-aggregate)
    lin2a_kernel<<<782, 256, 0, stream>>>(hb, wl2b, y2b);
    gather16_kernel<<<NNODES / 4, 256, 0, stream>>>(y2b, rowstart, srcSorted, agg2b);
    lin2b_kernel<<<782, 256, 0, stream>>>(agg2b, hb, wr2b, bl2, out);
}

// Round 9
// 160.562 us; speedup vs baseline: 2.9422x; 1.2708x over previous
//
#include <hip/hip_runtime.h>

#define NNODES 50000
#define EEDGES 800000
#define FIN 128
#define FH 128
#define FOUT 16
#define BN_EPS 1e-5f
#define NBIN 391      // ceil(50000/128) bins of 128 dst nodes
#define CAP 4096      // fixed edge capacity per bin (expected ~2046, max ~2250)
#define PCH 2048      // edges per partition block
#define NPB 391       // ceil(800000/2048)
#define NTILES 1563   // ceil(50000/32) lin1 row tiles

typedef short bf16x8 __attribute__((ext_vector_type(8)));
typedef float f32x4 __attribute__((ext_vector_type(4)));

__device__ inline unsigned short tobf16(float f) {
    unsigned int u = __float_as_uint(f);
    u += 0x7fffu + ((u >> 16) & 1u);   // RNE
    return (unsigned short)(u >> 16);
}
__device__ inline float frombf16(unsigned short h) {
    return __uint_as_float(((unsigned int)h) << 16);
}
__device__ inline unsigned packbf(float f0, float f1) {
    return (unsigned)tobf16(f0) | ((unsigned)tobf16(f1) << 16);
}
__device__ inline float lo16(unsigned u) { return __uint_as_float(u << 16); }
__device__ inline float hi16(unsigned u) { return __uint_as_float(u & 0xffff0000u); }

// ---------------- K1: pack x->bf16, W->bf16 (8 elems/thread, no atomics) ----------------
__global__ void pack_kernel(const float* __restrict__ x,
                            const float* __restrict__ Wl1, const float* __restrict__ Wr1,
                            const float* __restrict__ Wl2, const float* __restrict__ Wr2,
                            unsigned short* __restrict__ xb, unsigned short* __restrict__ wb) {
    int t = blockIdx.x * 256 + threadIdx.x;
    int base = t * 8;
    const float* srcp;
    unsigned short* dstp;
    int off;
    if (base < NNODES * FIN) {
        srcp = x; off = base; dstp = xb + base;
    } else {
        int w = base - NNODES * FIN;
        if (w >= 36864) return;
        dstp = wb + w;
        if (w < 16384)      { srcp = Wl1; off = w; }
        else if (w < 32768) { srcp = Wr1; off = w - 16384; }
        else if (w < 34816) { srcp = Wl2; off = w - 32768; }
        else                { srcp = Wr2; off = w - 34816; }
    }
    float4 f0 = *reinterpret_cast<const float4*>(srcp + off);
    float4 f1 = *reinterpret_cast<const float4*>(srcp + off + 4);
    uint4 r;
    r.x = packbf(f0.x, f0.y);
    r.y = packbf(f0.z, f0.w);
    r.z = packbf(f1.x, f1.y);
    r.w = packbf(f1.z, f1.w);
    *reinterpret_cast<uint4*>(dstp) = r;
}

// ---------------- K2: partition edges into fixed-capacity bins ----------------
__global__ void partition_kernel(const int* __restrict__ src, const int* __restrict__ dst,
                                 int* __restrict__ binFill, unsigned int* __restrict__ edgeBin) {
    __shared__ int hist[NBIN];
    __shared__ int runBase[NBIN];
    __shared__ int runFill[NBIN];
    int t = threadIdx.x;
    for (int i = t; i < NBIN; i += 256) { hist[i] = 0; runFill[i] = 0; }
    __syncthreads();
    int e0 = blockIdx.x * PCH;
    for (int i = 0; i < PCH / 256; ++i) {
        int e = e0 + i * 256 + t;
        if (e < EEDGES) atomicAdd(&hist[dst[e] >> 7], 1);
    }
    __syncthreads();
    for (int i = t; i < NBIN; i += 256) {
        int c = hist[i];
        if (c) runBase[i] = atomicAdd(&binFill[i], c);
    }
    __syncthreads();
    for (int i = 0; i < PCH / 256; ++i) {
        int e = e0 + i * 256 + t;
        if (e < EEDGES) {
            int d = dst[e];
            int b = d >> 7;
            int off = runBase[b] + atomicAdd(&runFill[b], 1);
            if (off < CAP)
                edgeBin[(size_t)b * CAP + off] = ((unsigned)(d & 127) << 17) | (unsigned)src[e];
        }
    }
}

// ---------------- K3: per-bin node histogram + local exclusive scan ----------------
__global__ void binscan_kernel(const unsigned int* __restrict__ edgeBin,
                               const int* __restrict__ binFill,
                               int* __restrict__ localPrefix) {
    __shared__ int cnt[128];
    __shared__ int sc[128];
    int b = blockIdx.x;
    int t = threadIdx.x;
    if (t < 128) cnt[t] = 0;
    __syncthreads();
    int n = binFill[b];
    for (int k = t; k < n; k += 256)
        atomicAdd(&cnt[edgeBin[(size_t)b * CAP + k] >> 17], 1);
    __syncthreads();
    if (t < 128) sc[t] = cnt[t];
    __syncthreads();
    for (int off = 1; off < 128; off <<= 1) {
        int v = (t < 128 && t >= off) ? sc[t - off] : 0;
        __syncthreads();
        if (t < 128) sc[t] += v;
        __syncthreads();
    }
    if (t < 128) localPrefix[b * 128 + t] = sc[t] - cnt[t];
}

// ---------------- K4: exclusive scan of 391 bin counts -> binOff ----------------
__global__ void scanbins_kernel(const int* __restrict__ binFill, int* __restrict__ binOff) {
    __shared__ int sh[512];
    int t = threadIdx.x;
    int v = (t < NBIN) ? binFill[t] : 0;
    sh[t] = v;
    __syncthreads();
    for (int off = 1; off < 512; off <<= 1) {
        int u = (t >= off) ? sh[t - off] : 0;
        __syncthreads();
        sh[t] += u;
        __syncthreads();
    }
    if (t < NBIN) binOff[t] = sh[t] - v;
}

// ---------------- K5: local bucket -> srcSorted; also writes rowstart ----------------
__global__ void local_bucket_kernel(const unsigned int* __restrict__ edgeBin,
                                    const int* __restrict__ binFill,
                                    const int* __restrict__ binOff,
                                    const int* __restrict__ localPrefix,
                                    int* __restrict__ srcSorted,
                                    int* __restrict__ rowstart) {
    __shared__ int wp[128];
    int b = blockIdx.x;
    int t = threadIdx.x;
    if (t < 128) {
        int node = b * 128 + t;
        int rs = binOff[b] + localPrefix[b * 128 + t];
        wp[t] = rs;
        if (node < NNODES) rowstart[node] = rs;
    }
    if (b == 0 && t == 128) rowstart[NNODES] = EEDGES;
    __syncthreads();
    int n = binFill[b];
    for (int k = t; k < n; k += 256) {
        unsigned c = edgeBin[(size_t)b * CAP + k];
        int p = atomicAdd(&wp[c >> 17], 1);
        srcSorted[p] = (int)(c & 0x1FFFF);
    }
}

// ---------------- gather 128 features (per-node, register accum) ----------------
__global__ void gather_bf16(const unsigned short* __restrict__ feat,
                            const int* __restrict__ rowstart,
                            const int* __restrict__ srcSorted,
                            unsigned short* __restrict__ aggout) {
    int tid = threadIdx.x;
    int i = blockIdx.x * 4 + (tid >> 6);
    int j = tid & 63;
    const unsigned int* fp = (const unsigned int*)feat;
    int k0 = rowstart[i], k1 = rowstart[i + 1];
    float a0 = 0.0f, a1 = 0.0f;
    int k = k0;
    for (; k + 4 <= k1; k += 4) {
        int s0 = srcSorted[k], s1 = srcSorted[k + 1], s2 = srcSorted[k + 2], s3 = srcSorted[k + 3];
        unsigned int u0 = fp[(size_t)s0 * 64 + j];
        unsigned int u1 = fp[(size_t)s1 * 64 + j];
        unsigned int u2 = fp[(size_t)s2 * 64 + j];
        unsigned int u3 = fp[(size_t)s3 * 64 + j];
        a0 += lo16(u0) + lo16(u1) + lo16(u2) + lo16(u3);
        a1 += hi16(u0) + hi16(u1) + hi16(u2) + hi16(u3);
    }
    for (; k < k1; ++k) {
        unsigned int u = fp[(size_t)srcSorted[k] * 64 + j];
        a0 += lo16(u);
        a1 += hi16(u);
    }
    float inv = 1.0f / (float)max(k1 - k0, 1);
    ((unsigned int*)aggout)[(size_t)i * 64 + j] = packbf(a0 * inv, a1 * inv);
}

// ---------------- lin1: persistent-weight MFMA + fused BN partials ----------------
__global__ void __launch_bounds__(256, 2)
lin1_persist(const unsigned short* __restrict__ aggb,
             const unsigned short* __restrict__ xb,
             const unsigned short* __restrict__ wl,
             const unsigned short* __restrict__ wr,
             const float* __restrict__ bias,
             unsigned short* __restrict__ hb,
             float* __restrict__ bnsum, float* __restrict__ bnsq) {
    __shared__ float bps[128];
    __shared__ float bpq[128];
    int tid = threadIdx.x;
    if (tid < 128) { bps[tid] = 0.0f; bpq[tid] = 0.0f; }
    __syncthreads();
    int wave = tid >> 6;
    int lane = tid & 63;
    int c = wave & 1;
    int rsub = wave >> 1;
    int lrow = lane & 15;
    int kg = lane >> 4;

    bf16x8 wlF[4][4], wrF[4][4];
    #pragma unroll
    for (int nf = 0; nf < 4; ++nf) {
        #pragma unroll
        for (int ks = 0; ks < 4; ++ks) {
            wlF[nf][ks] = *(const bf16x8*)(wl + (size_t)(c * 64 + nf * 16 + lrow) * 128 + ks * 32 + kg * 8);
            wrF[nf][ks] = *(const bf16x8*)(wr + (size_t)(c * 64 + nf * 16 + lrow) * 128 + ks * 32 + kg * 8);
        }
    }
    float bias_v[4];
    #pragma unroll
    for (int nf = 0; nf < 4; ++nf) bias_v[nf] = bias[c * 64 + nf * 16 + lrow];

    for (int tIt = blockIdx.x; tIt < NTILES; tIt += gridDim.x) {
        int rowA = tIt * 32 + rsub * 16 + lrow;
        int arow = min(rowA, NNODES - 1);
        bf16x8 aA[4], aX[4];
        #pragma unroll
        for (int ks = 0; ks < 4; ++ks) {
            aA[ks] = *(const bf16x8*)(aggb + (size_t)arow * 128 + ks * 32 + kg * 8);
            aX[ks] = *(const bf16x8*)(xb + (size_t)arow * 128 + ks * 32 + kg * 8);
        }
        f32x4 acc[4] = {};
        #pragma unroll
        for (int ks = 0; ks < 4; ++ks) {
            #pragma unroll
            for (int nf = 0; nf < 4; ++nf) {
                acc[nf] = __builtin_amdgcn_mfma_f32_16x16x32_bf16(aA[ks], wlF[nf][ks], acc[nf], 0, 0, 0);
                acc[nf] = __builtin_amdgcn_mfma_f32_16x16x32_bf16(aX[ks], wrF[nf][ks], acc[nf], 0, 0, 0);
            }
        }
        #pragma unroll
        for (int nf = 0; nf < 4; ++nf) {
            float s = 0.0f, q = 0.0f;
            #pragma unroll
            for (int rr = 0; rr < 4; ++rr) {
                int row = tIt * 32 + rsub * 16 + kg * 4 + rr;
                if (row < NNODES) {
                    unsigned short hv = tobf16(acc[nf][rr] + bias_v[nf]);
                    float vr = frombf16(hv);
                    hb[(size_t)row * 128 + c * 64 + nf * 16 + lrow] = hv;
                    s += vr; q += vr * vr;
                }
            }
            s += __shfl_xor(s, 16); s += __shfl_xor(s, 32);
            q += __shfl_xor(q, 16); q += __shfl_xor(q, 32);
            if (lane < 16) {
                atomicAdd(&bps[c * 64 + nf * 16 + lane], s);
                atomicAdd(&bpq[c * 64 + nf * 16 + lane], q);
            }
        }
    }
    __syncthreads();
    if (tid < 128) {
        atomicAdd(&bnsum[tid], bps[tid]);
        atomicAdd(&bnsq[tid], bpq[tid]);
    }
}

// ---------------- BN apply + PReLU + residual (bf16 x), in place on hb ----------------
__global__ void bn_apply_kernel(unsigned short* __restrict__ hb,
                                const unsigned short* __restrict__ xb,
                                const float* __restrict__ gamma, const float* __restrict__ beta,
                                const float* __restrict__ aptr,
                                const float* __restrict__ bnsum, const float* __restrict__ bnsq) {
    int idx = blockIdx.x * 256 + threadIdx.x;
    if (idx >= NNODES * FH) return;
    int j = idx & 127;
    const float invN = 1.0f / (float)NNODES;
    float mean = bnsum[j] * invN;
    float var = bnsq[j] * invN - mean * mean;
    float istd = rsqrtf(var + BN_EPS);
    float v = frombf16(hb[idx]);
    v = gamma[j] * (v - mean) * istd + beta[j];
    float a = aptr[0];
    v = (v >= 0.0f) ? v : a * v;
    hb[idx] = tobf16(v + frombf16(xb[idx]));
}

// ---------------- y2 = hb @ Wl2^T (bf16 out, [N,16]) ----------------
__global__ void lin2a_kernel(const unsigned short* __restrict__ hb,
                             const unsigned short* __restrict__ wl,
                             unsigned short* __restrict__ y2) {
    int wave = threadIdx.x >> 6;
    int lane = threadIdx.x & 63;
    int row0 = blockIdx.x * 64 + wave * 16;
    int lrow = lane & 15;
    int kg = lane >> 4;
    int arow = min(row0 + lrow, NNODES - 1);
    f32x4 acc = {};
    #pragma unroll
    for (int ks = 0; ks < 4; ++ks) {
        bf16x8 a = *(const bf16x8*)(hb + (size_t)arow * 128 + ks * 32 + kg * 8);
        bf16x8 b = *(const bf16x8*)(wl + (size_t)lrow * 128 + ks * 32 + kg * 8);
        acc = __builtin_amdgcn_mfma_f32_16x16x32_bf16(a, b, acc, 0, 0, 0);
    }
    #pragma unroll
    for (int r = 0; r < 4; ++r) {
        int row = row0 + kg * 4 + r;
        if (row < NNODES)
            y2[(size_t)row * 16 + lrow] = tobf16(acc[r]);
    }
}

// ---------------- gather 16 features (8 lanes/edge, 8 edges in flight) ----------------
__global__ void gather16_kernel(const unsigned short* __restrict__ y2,
                                const int* __restrict__ rowstart,
                                const int* __restrict__ srcSorted,
                                unsigned short* __restrict__ agg2) {
    int tid = threadIdx.x;
    int i = blockIdx.x * 4 + (tid >> 6);
    int lane = tid & 63;
    int e = lane >> 3;
    int j = lane & 7;
    const unsigned int* yp = (const unsigned int*)y2;
    int k0 = rowstart[i], k1 = rowstart[i + 1];
    float a0 = 0.0f, a1 = 0.0f;
    for (int k = k0; k < k1; k += 8) {
        int kk = k + e;
        if (kk < k1) {
            unsigned u = yp[(size_t)srcSorted[kk] * 8 + j];
            a0 += lo16(u);
            a1 += hi16(u);
        }
    }
    a0 += __shfl_xor(a0, 8);  a1 += __shfl_xor(a1, 8);
    a0 += __shfl_xor(a0, 16); a1 += __shfl_xor(a1, 16);
    a0 += __shfl_xor(a0, 32); a1 += __shfl_xor(a1, 32);
    if (e == 0) {
        float inv = 1.0f / (float)max(k1 - k0, 1);
        ((unsigned int*)agg2)[(size_t)i * 8 + j] = packbf(a0 * inv, a1 * inv);
    }
}

// ---------------- out = agg2 + hb@Wr2^T + bl2 -> log_softmax ----------------
__global__ void lin2b_kernel(const unsigned short* __restrict__ agg2,
                             const unsigned short* __restrict__ hb,
                             const unsigned short* __restrict__ wr,
                             const float* __restrict__ bias,
                             float* __restrict__ out) {
    int wave = threadIdx.x >> 6;
    int lane = threadIdx.x & 63;
    int row0 = blockIdx.x * 64 + wave * 16;
    int lrow = lane & 15;
    int kg = lane >> 4;
    int arow = min(row0 + lrow, NNODES - 1);
    f32x4 acc = {};
    #pragma unroll
    for (int ks = 0; ks < 4; ++ks) {
        bf16x8 a = *(const bf16x8*)(hb + (size_t)arow * 128 + ks * 32 + kg * 8);
        bf16x8 b = *(const bf16x8*)(wr + (size_t)lrow * 128 + ks * 32 + kg * 8);
        acc = __builtin_amdgcn_mfma_f32_16x16x32_bf16(a, b, acc, 0, 0, 0);
    }
    float bl = bias[lrow];
    #pragma unroll
    for (int r = 0; r < 4; ++r) {
        int row = row0 + kg * 4 + r;
        int rowc = min(row, NNODES - 1);
        float v = acc[r] + bl + frombf16(agg2[(size_t)rowc * 16 + lrow]);
        float m = v;
        for (int s = 1; s < 16; s <<= 1) m = fmaxf(m, __shfl_xor(m, s, 16));
        float ex = expf(v - m);
        float se = ex;
        for (int s = 1; s < 16; s <<= 1) se += __shfl_xor(se, s, 16);
        if (row < NNODES)
            out[(size_t)row * FOUT + lrow] = v - m - logf(se);
    }
}

extern "C" void kernel_launch(void* const* d_in, const int* in_sizes, int n_in,
                              void* d_out, int out_size, void* d_ws, size_t ws_size,
                              hipStream_t stream) {
    const float* x    = (const float*)d_in[0];
    const int*   ei   = (const int*)d_in[1];
    const int*   src  = ei;
    const int*   dst  = ei + EEDGES;
    const float* Wl1  = (const float*)d_in[2];
    const float* bl1  = (const float*)d_in[3];
    const float* Wr1  = (const float*)d_in[4];
    const float* Wl2  = (const float*)d_in[5];
    const float* bl2  = (const float*)d_in[6];
    const float* Wr2  = (const float*)d_in[7];
    const float* gamma= (const float*)d_in[8];
    const float* beta = (const float*)d_in[9];
    const float* a    = (const float*)d_in[10];
    float* out = (float*)d_out;

    char* W = (char*)d_ws;
    unsigned short* xb    = (unsigned short*)(W + 0);           // 12,800,000 B
    unsigned short* hb    = (unsigned short*)(W + 12800000);    // 12,800,000 B
    unsigned int*  edgeBin= (unsigned int*)(W + 25600000);      // 6,406,144 B (dead after local_bucket)
    unsigned short* aggb  = (unsigned short*)(W + 25600000);    // 12,800,000 B (overlays edgeBin)
    unsigned short* y2b   = (unsigned short*)(W + 25600000);    // 1,600,000 B (overlays aggb)
    unsigned short* agg2b = (unsigned short*)(W + 27200000);    // 1,600,000 B
    unsigned short* wb    = (unsigned short*)(W + 38400000);    // 73,728 B
    int* binFill  = (int*)(W + 38473728);                       // 1,564 B
    float* bnsum  = (float*)(W + 38475292);                     // 512 B
    float* bnsq   = (float*)(W + 38475804);                     // 512 B
    int* binOff   = (int*)(W + 38476316);                       // 1,564 B
    int* localPrefix = (int*)(W + 38477880);                    // 200,192 B
    int* rowstart = (int*)(W + 38678072);                       // 200,004 B
    int* srcSorted= (int*)(W + 38878076);                       // 3,200,000 B

    unsigned short* wl1b = wb;
    unsigned short* wr1b = wb + 16384;
    unsigned short* wl2b = wb + 32768;
    unsigned short* wr2b = wb + 34816;

    // zero binFill + bnsum + bnsq (contiguous 2,588 B)
    hipMemsetAsync(binFill, 0, (size_t)2588, stream);

    pack_kernel<<<3143, 256, 0, stream>>>(x, Wl1, Wr1, Wl2, Wr2, xb, wb);
    partition_kernel<<<NPB, 256, 0, stream>>>(src, dst, binFill, edgeBin);
    binscan_kernel<<<NBIN, 256, 0, stream>>>(edgeBin, binFill, localPrefix);
    scanbins_kernel<<<1, 512, 0, stream>>>(binFill, binOff);
    local_bucket_kernel<<<NBIN, 256, 0, stream>>>(edgeBin, binFill, binOff, localPrefix,
                                                  srcSorted, rowstart);

    // layer 1
    gather_bf16<<<NNODES / 4, 256, 0, stream>>>(xb, rowstart, srcSorted, aggb);
    lin1_persist<<<512, 256, 0, stream>>>(aggb, xb, wl1b, wr1b, bl1, hb, bnsum, bnsq);
    bn_apply_kernel<<<25000, 256, 0, stream>>>(hb, xb, gamma, beta, a, bnsum, bnsq);

    // layer 2 (transform-then-aggregate)
    lin2a_kernel<<<782, 256, 0, stream>>>(hb, wl2b, y2b);
    gather16_kernel<<<NNODES / 4, 256, 0, stream>>>(y2b, rowstart, srcSorted, agg2b);
    lin2b_kernel<<<782, 256, 0, stream>>>(agg2b, hb, wr2b, bl2, out);
}

// Round 10
// 141.914 us; speedup vs baseline: 3.3288x; 1.1314x over previous
//
#include <hip/hip_runtime.h>

#define NNODES 50000
#define EEDGES 800000
#define FIN 128
#define FH 128
#define FOUT 16
#define BN_EPS 1e-5f
#define NBIN 391      // ceil(50000/128) bins of 128 dst nodes
#define CAP 4096      // fixed edge capacity per bin (expected ~2046)
#define PCH 2048      // edges per partition block
#define NPB 391       // ceil(800000/2048)
#define NTILES 1563   // ceil(50000/32) lin1 row tiles
#define PACKBLKS 3143 // 6,436,864 elems / (256*8)

typedef short bf16x8 __attribute__((ext_vector_type(8)));
typedef float f32x4 __attribute__((ext_vector_type(4)));

__device__ inline unsigned short tobf16(float f) {
    unsigned int u = __float_as_uint(f);
    u += 0x7fffu + ((u >> 16) & 1u);   // RNE
    return (unsigned short)(u >> 16);
}
__device__ inline float frombf16(unsigned short h) {
    return __uint_as_float(((unsigned int)h) << 16);
}
__device__ inline unsigned packbf(float f0, float f1) {
    return (unsigned)tobf16(f0) | ((unsigned)tobf16(f1) << 16);
}
__device__ inline float lo16(unsigned u) { return __uint_as_float(u << 16); }
__device__ inline float hi16(unsigned u) { return __uint_as_float(u & 0xffff0000u); }

// ---------------- K1: partition (blocks 0..390) || pack (blocks 391..) ----------------
__global__ void part_pack_kernel(const int* __restrict__ src, const int* __restrict__ dst,
                                 int* __restrict__ binFill, unsigned int* __restrict__ edgeBin,
                                 const float* __restrict__ x,
                                 const float* __restrict__ Wl1, const float* __restrict__ Wr1,
                                 const float* __restrict__ Wl2, const float* __restrict__ Wr2,
                                 unsigned short* __restrict__ xb, unsigned short* __restrict__ wb) {
    __shared__ int hist[NBIN];
    __shared__ int runBase[NBIN];
    __shared__ int runFill[NBIN];
    int t = threadIdx.x;
    if (blockIdx.x < NPB) {
        // ---- partition path ----
        for (int i = t; i < NBIN; i += 256) { hist[i] = 0; runFill[i] = 0; }
        __syncthreads();
        int e0 = blockIdx.x * PCH;
        for (int i = 0; i < PCH / 256; ++i) {
            int e = e0 + i * 256 + t;
            if (e < EEDGES) atomicAdd(&hist[dst[e] >> 7], 1);
        }
        __syncthreads();
        for (int i = t; i < NBIN; i += 256) {
            int c = hist[i];
            if (c) runBase[i] = atomicAdd(&binFill[i], c);
        }
        __syncthreads();
        for (int i = 0; i < PCH / 256; ++i) {
            int e = e0 + i * 256 + t;
            if (e < EEDGES) {
                int d = dst[e];
                int b = d >> 7;
                int off = runBase[b] + atomicAdd(&runFill[b], 1);
                if (off < CAP)
                    edgeBin[(size_t)b * CAP + off] = ((unsigned)(d & 127) << 17) | (unsigned)src[e];
            }
        }
    } else {
        // ---- pack path: 8 elems/thread ----
        int tt = (blockIdx.x - NPB) * 256 + t;
        int base = tt * 8;
        const float* srcp;
        unsigned short* dstp;
        int off;
        if (base < NNODES * FIN) {
            srcp = x; off = base; dstp = xb + base;
        } else {
            int w = base - NNODES * FIN;
            if (w >= 36864) return;
            dstp = wb + w;
            if (w < 16384)      { srcp = Wl1; off = w; }
            else if (w < 32768) { srcp = Wr1; off = w - 16384; }
            else if (w < 34816) { srcp = Wl2; off = w - 32768; }
            else                { srcp = Wr2; off = w - 34816; }
        }
        float4 f0 = *reinterpret_cast<const float4*>(srcp + off);
        float4 f1 = *reinterpret_cast<const float4*>(srcp + off + 4);
        uint4 r;
        r.x = packbf(f0.x, f0.y);
        r.y = packbf(f0.z, f0.w);
        r.z = packbf(f1.x, f1.y);
        r.w = packbf(f1.z, f1.w);
        *reinterpret_cast<uint4*>(dstp) = r;
    }
}

// ---------------- K2: binscan (blocks 0..390) || scanbins (block 391) ----------------
__global__ void binscan_scan_kernel(const unsigned int* __restrict__ edgeBin,
                                    const int* __restrict__ binFill,
                                    int* __restrict__ localPrefix,
                                    int* __restrict__ binOff) {
    int t = threadIdx.x;
    if (blockIdx.x < NBIN) {
        __shared__ int cnt[128];
        __shared__ int sc[128];
        int b = blockIdx.x;
        if (t < 128) cnt[t] = 0;
        __syncthreads();
        int n = binFill[b];
        for (int k = t; k < n; k += 256)
            atomicAdd(&cnt[edgeBin[(size_t)b * CAP + k] >> 17], 1);
        __syncthreads();
        if (t < 128) sc[t] = cnt[t];
        __syncthreads();
        for (int off = 1; off < 128; off <<= 1) {
            int v = (t < 128 && t >= off) ? sc[t - off] : 0;
            __syncthreads();
            if (t < 128) sc[t] += v;
            __syncthreads();
        }
        if (t < 128) localPrefix[b * 128 + t] = sc[t] - cnt[t];
    } else {
        // scan 391 bin counts with 256 threads (2 slots/thread Hillis-Steele over 512)
        __shared__ int sh[512];
        int v0 = (t < NBIN) ? binFill[t] : 0;
        int v1 = (t + 256 < NBIN) ? binFill[t + 256] : 0;
        sh[t] = v0; sh[t + 256] = v1;
        __syncthreads();
        for (int off = 1; off < 512; off <<= 1) {
            int a0 = (t >= off) ? sh[t - off] : 0;
            int a1 = (t + 256 >= off) ? sh[t + 256 - off] : 0;
            __syncthreads();
            sh[t] += a0; sh[t + 256] += a1;
            __syncthreads();
        }
        if (t < NBIN) binOff[t] = sh[t] - v0;
        if (t + 256 < NBIN) binOff[t + 256] = sh[t + 256] - v1;
    }
}

// ---------------- K3: local bucket -> srcSorted; also writes rowstart ----------------
__global__ void local_bucket_kernel(const unsigned int* __restrict__ edgeBin,
                                    const int* __restrict__ binFill,
                                    const int* __restrict__ binOff,
                                    const int* __restrict__ localPrefix,
                                    int* __restrict__ srcSorted,
                                    int* __restrict__ rowstart) {
    __shared__ int wp[128];
    int b = blockIdx.x;
    int t = threadIdx.x;
    if (t < 128) {
        int node = b * 128 + t;
        int rs = binOff[b] + localPrefix[b * 128 + t];
        wp[t] = rs;
        if (node < NNODES) rowstart[node] = rs;
    }
    if (b == 0 && t == 128) rowstart[NNODES] = EEDGES;
    __syncthreads();
    int n = binFill[b];
    for (int k = t; k < n; k += 256) {
        unsigned c = edgeBin[(size_t)b * CAP + k];
        int p = atomicAdd(&wp[c >> 17], 1);
        srcSorted[p] = (int)(c & 0x1FFFF);
    }
}

// ---------------- K4: gather 128 features (per-node, 8-deep MLP) ----------------
__global__ void gather_bf16(const unsigned short* __restrict__ feat,
                            const int* __restrict__ rowstart,
                            const int* __restrict__ srcSorted,
                            unsigned short* __restrict__ aggout) {
    int tid = threadIdx.x;
    int i = blockIdx.x * 4 + (tid >> 6);
    int j = tid & 63;
    const unsigned int* fp = (const unsigned int*)feat;
    int k0 = rowstart[i], k1 = rowstart[i + 1];
    float a0 = 0.0f, a1 = 0.0f;
    int k = k0;
    for (; k + 8 <= k1; k += 8) {
        int s0 = srcSorted[k],     s1 = srcSorted[k + 1], s2 = srcSorted[k + 2], s3 = srcSorted[k + 3];
        int s4 = srcSorted[k + 4], s5 = srcSorted[k + 5], s6 = srcSorted[k + 6], s7 = srcSorted[k + 7];
        unsigned int u0 = fp[(size_t)s0 * 64 + j];
        unsigned int u1 = fp[(size_t)s1 * 64 + j];
        unsigned int u2 = fp[(size_t)s2 * 64 + j];
        unsigned int u3 = fp[(size_t)s3 * 64 + j];
        unsigned int u4 = fp[(size_t)s4 * 64 + j];
        unsigned int u5 = fp[(size_t)s5 * 64 + j];
        unsigned int u6 = fp[(size_t)s6 * 64 + j];
        unsigned int u7 = fp[(size_t)s7 * 64 + j];
        a0 += lo16(u0) + lo16(u1) + lo16(u2) + lo16(u3) + lo16(u4) + lo16(u5) + lo16(u6) + lo16(u7);
        a1 += hi16(u0) + hi16(u1) + hi16(u2) + hi16(u3) + hi16(u4) + hi16(u5) + hi16(u6) + hi16(u7);
    }
    for (; k + 4 <= k1; k += 4) {
        int s0 = srcSorted[k], s1 = srcSorted[k + 1], s2 = srcSorted[k + 2], s3 = srcSorted[k + 3];
        unsigned int u0 = fp[(size_t)s0 * 64 + j];
        unsigned int u1 = fp[(size_t)s1 * 64 + j];
        unsigned int u2 = fp[(size_t)s2 * 64 + j];
        unsigned int u3 = fp[(size_t)s3 * 64 + j];
        a0 += lo16(u0) + lo16(u1) + lo16(u2) + lo16(u3);
        a1 += hi16(u0) + hi16(u1) + hi16(u2) + hi16(u3);
    }
    for (; k < k1; ++k) {
        unsigned int u = fp[(size_t)srcSorted[k] * 64 + j];
        a0 += lo16(u);
        a1 += hi16(u);
    }
    float inv = 1.0f / (float)max(k1 - k0, 1);
    ((unsigned int*)aggout)[(size_t)i * 64 + j] = packbf(a0 * inv, a1 * inv);
}

// ---------------- K5: lin1 persistent-weight MFMA + fused BN partials ----------------
__global__ void __launch_bounds__(256, 2)
lin1_persist(const unsigned short* __restrict__ aggb,
             const unsigned short* __restrict__ xb,
             const unsigned short* __restrict__ wl,
             const unsigned short* __restrict__ wr,
             const float* __restrict__ bias,
             unsigned short* __restrict__ hb,
             float* __restrict__ bnsum, float* __restrict__ bnsq) {
    __shared__ float bps[128];
    __shared__ float bpq[128];
    int tid = threadIdx.x;
    if (tid < 128) { bps[tid] = 0.0f; bpq[tid] = 0.0f; }
    __syncthreads();
    int wave = tid >> 6;
    int lane = tid & 63;
    int c = wave & 1;
    int rsub = wave >> 1;
    int lrow = lane & 15;
    int kg = lane >> 4;

    bf16x8 wlF[4][4], wrF[4][4];
    #pragma unroll
    for (int nf = 0; nf < 4; ++nf) {
        #pragma unroll
        for (int ks = 0; ks < 4; ++ks) {
            wlF[nf][ks] = *(const bf16x8*)(wl + (size_t)(c * 64 + nf * 16 + lrow) * 128 + ks * 32 + kg * 8);
            wrF[nf][ks] = *(const bf16x8*)(wr + (size_t)(c * 64 + nf * 16 + lrow) * 128 + ks * 32 + kg * 8);
        }
    }
    float bias_v[4];
    #pragma unroll
    for (int nf = 0; nf < 4; ++nf) bias_v[nf] = bias[c * 64 + nf * 16 + lrow];

    for (int tIt = blockIdx.x; tIt < NTILES; tIt += gridDim.x) {
        int rowA = tIt * 32 + rsub * 16 + lrow;
        int arow = min(rowA, NNODES - 1);
        bf16x8 aA[4], aX[4];
        #pragma unroll
        for (int ks = 0; ks < 4; ++ks) {
            aA[ks] = *(const bf16x8*)(aggb + (size_t)arow * 128 + ks * 32 + kg * 8);
            aX[ks] = *(const bf16x8*)(xb + (size_t)arow * 128 + ks * 32 + kg * 8);
        }
        f32x4 acc[4] = {};
        #pragma unroll
        for (int ks = 0; ks < 4; ++ks) {
            #pragma unroll
            for (int nf = 0; nf < 4; ++nf) {
                acc[nf] = __builtin_amdgcn_mfma_f32_16x16x32_bf16(aA[ks], wlF[nf][ks], acc[nf], 0, 0, 0);
                acc[nf] = __builtin_amdgcn_mfma_f32_16x16x32_bf16(aX[ks], wrF[nf][ks], acc[nf], 0, 0, 0);
            }
        }
        #pragma unroll
        for (int nf = 0; nf < 4; ++nf) {
            float s = 0.0f, q = 0.0f;
            #pragma unroll
            for (int rr = 0; rr < 4; ++rr) {
                int row = tIt * 32 + rsub * 16 + kg * 4 + rr;
                if (row < NNODES) {
                    unsigned short hv = tobf16(acc[nf][rr] + bias_v[nf]);
                    float vr = frombf16(hv);
                    hb[(size_t)row * 128 + c * 64 + nf * 16 + lrow] = hv;
                    s += vr; q += vr * vr;
                }
            }
            s += __shfl_xor(s, 16); s += __shfl_xor(s, 32);
            q += __shfl_xor(q, 16); q += __shfl_xor(q, 32);
            if (lane < 16) {
                atomicAdd(&bps[c * 64 + nf * 16 + lane], s);
                atomicAdd(&bpq[c * 64 + nf * 16 + lane], q);
            }
        }
    }
    __syncthreads();
    if (tid < 128) {
        atomicAdd(&bnsum[tid], bps[tid]);
        atomicAdd(&bnsq[tid], bpq[tid]);
    }
}

// ---------------- K6: fused BN apply + PReLU + residual + y2 = h'@Wl2^T ----------------
// Per block: 64 rows. Reads pre-BN hb, writes post-BN hb (in place) AND y2.
__global__ void bn_lin2a_kernel(unsigned short* __restrict__ hb,
                                const unsigned short* __restrict__ xb,
                                const float* __restrict__ gamma, const float* __restrict__ beta,
                                const float* __restrict__ aptr,
                                const float* __restrict__ bnsum, const float* __restrict__ bnsq,
                                const unsigned short* __restrict__ wl,
                                unsigned short* __restrict__ y2) {
    __shared__ float scs[128];
    __shared__ float shs[128];
    int tid = threadIdx.x;
    if (tid < 128) {
        const float invN = 1.0f / (float)NNODES;
        float mean = bnsum[tid] * invN;
        float var = bnsq[tid] * invN - mean * mean;
        float istd = rsqrtf(var + BN_EPS);
        float sc = gamma[tid] * istd;
        scs[tid] = sc;
        shs[tid] = beta[tid] - mean * sc;
    }
    __syncthreads();
    float aP = aptr[0];
    int wave = tid >> 6;
    int lane = tid & 63;
    int row0 = blockIdx.x * 64 + wave * 16;
    int lrow = lane & 15;
    int kg = lane >> 4;
    int rowA = row0 + lrow;
    int arow = min(rowA, NNODES - 1);
    f32x4 acc = {};
    #pragma unroll
    for (int ks = 0; ks < 4; ++ks) {
        bf16x8 hv = *(const bf16x8*)(hb + (size_t)arow * 128 + ks * 32 + kg * 8);
        bf16x8 xv = *(const bf16x8*)(xb + (size_t)arow * 128 + ks * 32 + kg * 8);
        bf16x8 nv;
        #pragma unroll
        for (int e = 0; e < 8; ++e) {
            int f = ks * 32 + kg * 8 + e;
            float v = frombf16((unsigned short)hv[e]) * scs[f] + shs[f];
            v = (v >= 0.0f) ? v : aP * v;
            v += frombf16((unsigned short)xv[e]);
            nv[e] = (short)tobf16(v);
        }
        if (rowA < NNODES)
            *(bf16x8*)(hb + (size_t)arow * 128 + ks * 32 + kg * 8) = nv;
        bf16x8 b = *(const bf16x8*)(wl + (size_t)lrow * 128 + ks * 32 + kg * 8);
        acc = __builtin_amdgcn_mfma_f32_16x16x32_bf16(nv, b, acc, 0, 0, 0);
    }
    #pragma unroll
    for (int r = 0; r < 4; ++r) {
        int row = row0 + kg * 4 + r;
        if (row < NNODES)
            y2[(size_t)row * 16 + lrow] = tobf16(acc[r]);
    }
}

// ---------------- K7: gather 16 features (8 lanes/edge, 8 edges in flight) ----------------
__global__ void gather16_kernel(const unsigned short* __restrict__ y2,
                                const int* __restrict__ rowstart,
                                const int* __restrict__ srcSorted,
                                unsigned short* __restrict__ agg2) {
    int tid = threadIdx.x;
    int i = blockIdx.x * 4 + (tid >> 6);
    int lane = tid & 63;
    int e = lane >> 3;
    int j = lane & 7;
    const unsigned int* yp = (const unsigned int*)y2;
    int k0 = rowstart[i], k1 = rowstart[i + 1];
    float a0 = 0.0f, a1 = 0.0f;
    for (int k = k0; k < k1; k += 8) {
        int kk = k + e;
        if (kk < k1) {
            unsigned u = yp[(size_t)srcSorted[kk] * 8 + j];
            a0 += lo16(u);
            a1 += hi16(u);
        }
    }
    a0 += __shfl_xor(a0, 8);  a1 += __shfl_xor(a1, 8);
    a0 += __shfl_xor(a0, 16); a1 += __shfl_xor(a1, 16);
    a0 += __shfl_xor(a0, 32); a1 += __shfl_xor(a1, 32);
    if (e == 0) {
        float inv = 1.0f / (float)max(k1 - k0, 1);
        ((unsigned int*)agg2)[(size_t)i * 8 + j] = packbf(a0 * inv, a1 * inv);
    }
}

// ---------------- K8: out = agg2 + hb@Wr2^T + bl2 -> log_softmax ----------------
__global__ void lin2b_kernel(const unsigned short* __restrict__ agg2,
                             const unsigned short* __restrict__ hb,
                             const unsigned short* __restrict__ wr,
                             const float* __restrict__ bias,
                             float* __restrict__ out) {
    int wave = threadIdx.x >> 6;
    int lane = threadIdx.x & 63;
    int row0 = blockIdx.x * 64 + wave * 16;
    int lrow = lane & 15;
    int kg = lane >> 4;
    int arow = min(row0 + lrow, NNODES - 1);
    f32x4 acc = {};
    #pragma unroll
    for (int ks = 0; ks < 4; ++ks) {
        bf16x8 a = *(const bf16x8*)(hb + (size_t)arow * 128 + ks * 32 + kg * 8);
        bf16x8 b = *(const bf16x8*)(wr + (size_t)lrow * 128 + ks * 32 + kg * 8);
        acc = __builtin_amdgcn_mfma_f32_16x16x32_bf16(a, b, acc, 0, 0, 0);
    }
    float bl = bias[lrow];
    #pragma unroll
    for (int r = 0; r < 4; ++r) {
        int row = row0 + kg * 4 + r;
        int rowc = min(row, NNODES - 1);
        float v = acc[r] + bl + frombf16(agg2[(size_t)rowc * 16 + lrow]);
        float m = v;
        for (int s = 1; s < 16; s <<= 1) m = fmaxf(m, __shfl_xor(m, s, 16));
        float ex = expf(v - m);
        float se = ex;
        for (int s = 1; s < 16; s <<= 1) se += __shfl_xor(se, s, 16);
        if (row < NNODES)
            out[(size_t)row * FOUT + lrow] = v - m - logf(se);
    }
}

extern "C" void kernel_launch(void* const* d_in, const int* in_sizes, int n_in,
                              void* d_out, int out_size, void* d_ws, size_t ws_size,
                              hipStream_t stream) {
    const float* x    = (const float*)d_in[0];
    const int*   ei   = (const int*)d_in[1];
    const int*   src  = ei;
    const int*   dst  = ei + EEDGES;
    const float* Wl1  = (const float*)d_in[2];
    const float* bl1  = (const float*)d_in[3];
    const float* Wr1  = (const float*)d_in[4];
    const float* Wl2  = (const float*)d_in[5];
    const float* bl2  = (const float*)d_in[6];
    const float* Wr2  = (const float*)d_in[7];
    const float* gamma= (const float*)d_in[8];
    const float* beta = (const float*)d_in[9];
    const float* a    = (const float*)d_in[10];
    float* out = (float*)d_out;

    char* W = (char*)d_ws;
    unsigned short* xb    = (unsigned short*)(W + 0);           // 12,800,000 B
    unsigned short* hb    = (unsigned short*)(W + 12800000);    // 12,800,000 B
    unsigned int*  edgeBin= (unsigned int*)(W + 25600000);      // 6,406,144 B (dead after K3)
    unsigned short* aggb  = (unsigned short*)(W + 25600000);    // 12,800,000 B (overlays edgeBin)
    unsigned short* y2b   = (unsigned short*)(W + 25600000);    // 1,600,000 B (overlays aggb)
    unsigned short* agg2b = (unsigned short*)(W + 27200000);    // 1,600,000 B
    unsigned short* wb    = (unsigned short*)(W + 38400000);    // 73,728 B
    int* binFill  = (int*)(W + 38473728);                       // 1,564 B
    float* bnsum  = (float*)(W + 38475292);                     // 512 B
    float* bnsq   = (float*)(W + 38475804);                     // 512 B
    int* binOff   = (int*)(W + 38476316);                       // 1,564 B
    int* localPrefix = (int*)(W + 38477880);                    // 200,192 B
    int* rowstart = (int*)(W + 38678072);                       // 200,004 B
    int* srcSorted= (int*)(W + 38878076);                       // 3,200,000 B

    unsigned short* wl1b = wb;
    unsigned short* wr1b = wb + 16384;
    unsigned short* wl2b = wb + 32768;
    unsigned short* wr2b = wb + 34816;

    // zero binFill + bnsum + bnsq (contiguous 2,588 B)
    hipMemsetAsync(binFill, 0, (size_t)2588, stream);

    part_pack_kernel<<<NPB + PACKBLKS, 256, 0, stream>>>(src, dst, binFill, edgeBin,
                                                         x, Wl1, Wr1, Wl2, Wr2, xb, wb);
    binscan_scan_kernel<<<NBIN + 1, 256, 0, stream>>>(edgeBin, binFill, localPrefix, binOff);
    local_bucket_kernel<<<NBIN, 256, 0, stream>>>(edgeBin, binFill, binOff, localPrefix,
                                                  srcSorted, rowstart);

    // layer 1
    gather_bf16<<<NNODES / 4, 256, 0, stream>>>(xb, rowstart, srcSorted, aggb);
    lin1_persist<<<512, 256, 0, stream>>>(aggb, xb, wl1b, wr1b, bl1, hb, bnsum, bnsq);

    // fused BN/PReLU/residual + lin2a
    bn_lin2a_kernel<<<782, 256, 0, stream>>>(hb, xb, gamma, beta, a, bnsum, bnsq, wl2b, y2b);

    // layer 2 aggregate + final
    gather16_kernel<<<NNODES / 4, 256, 0, stream>>>(y2b, rowstart, srcSorted, agg2b);
    lin2b_kernel<<<782, 256, 0, stream>>>(agg2b, hb, wr2b, bl2, out);
}